// Round 16
// baseline (555.809 us; speedup 1.0000x reference)
//
#include <hip/hip_runtime.h>

#define BSZ 16384

typedef __attribute__((ext_vector_type(8))) short bf16x8;
typedef __attribute__((ext_vector_type(4))) float f32x4;
typedef __attribute__((ext_vector_type(8))) unsigned short u16x8;

// pack fp32 -> interleaved (hi bf16 | lo bf16 << 16); hi+lo ~= x within 2^-16 rel
__device__ inline unsigned packbf(float v) {
    unsigned u = __float_as_uint(v);
    unsigned r = u + (0x7fffu + ((u >> 16) & 1u));
    unsigned hi = r >> 16;
    float rem = v - __uint_as_float(r & 0xffff0000u);
    unsigned lu = __float_as_uint(rem);
    unsigned lo = (lu + (0x7fffu + ((lu >> 16) & 1u))) >> 16;
    return hi | (lo << 16);
}
__device__ inline float unpackf(unsigned u) {
    return __uint_as_float(u << 16) + __uint_as_float(u & 0xffff0000u);
}
// 8 interleaved elems (two uint4) -> hi-plane and lo-plane bf16x8 frags
__device__ inline void unpack8(const uint4 p0, const uint4 p1, bf16x8& hi, bf16x8& lo) {
    union { unsigned u[4]; bf16x8 v; } H, L;
    H.u[0] = __builtin_amdgcn_perm(p0.y, p0.x, 0x05040100u);
    H.u[1] = __builtin_amdgcn_perm(p0.w, p0.z, 0x05040100u);
    H.u[2] = __builtin_amdgcn_perm(p1.y, p1.x, 0x05040100u);
    H.u[3] = __builtin_amdgcn_perm(p1.w, p1.z, 0x05040100u);
    L.u[0] = __builtin_amdgcn_perm(p0.y, p0.x, 0x07060302u);
    L.u[1] = __builtin_amdgcn_perm(p0.w, p0.z, 0x07060302u);
    L.u[2] = __builtin_amdgcn_perm(p1.y, p1.x, 0x07060302u);
    L.u[3] = __builtin_amdgcn_perm(p1.w, p1.z, 0x07060302u);
    hi = H.v; lo = L.v;
}

// ---------------- merged preprocessing kernel -----------------------------
struct WFA {
    const float* src[18];
    unsigned short* dst[18];
    int start[19];
    int kslog[18];
};
struct PrepAll {
    const float* psrc[3]; unsigned* pdst[3]; int pstart[4];
    const float* c0; const float* c1; const float* c2;
    float* cbn;
    unsigned short* f0; unsigned short* f1; unsigned short* f2;
    WFA wa;
    const float* iw[2]; const float* ib[2];
    const float* ow[2]; const float* ob[2];
    unsigned* wcomb[2]; float* bcomb[2];
};
__global__ __launch_bounds__(256) void prep_all(PrepAll pa) {
    __shared__ float shm[8192];
    const int bid = blockIdx.x;
    const int tid = threadIdx.x;
    if (bid < 640) {
        const int base = bid << 10;
        int seg = 0;
        if (base >= pa.pstart[1]) seg = 1;
        if (base >= pa.pstart[2]) seg = 2;
        const int off = base - pa.pstart[seg] + (tid << 2);
        const float4 v = *(const float4*)(pa.psrc[seg] + off);
        uint4 u;
        u.x = packbf(v.x); u.y = packbf(v.y); u.z = packbf(v.z); u.w = packbf(v.w);
        *(uint4*)(pa.pdst[seg] + off) = u;
    } else if (bid < 680) {
        const int r = (bid - 640) * 256 + tid;
        const float* src; int off;
        if (r < 2048) { src = pa.c0; off = r; }
        else if (r < 6144) { src = pa.c1; off = r - 2048; }
        else { src = pa.c2; off = r - 6144; }
        const float4* p = (const float4*)(src + (size_t)off * 64);
        float s = 0.f;
        #pragma unroll
        for (int c = 0; c < 16; ++c) {
            float4 v = p[c];
            s += v.x * v.x + v.y * v.y + v.z * v.z + v.w * v.w;
        }
        pa.cbn[r] = s;
    } else if (bid < 1320) {
        int g = (bid - 680) * 256 + tid;
        const float* src; unsigned short* dst;
        if (g < 32768) { src = pa.c0; dst = pa.f0; }
        else if (g < 98304) { src = pa.c1; dst = pa.f1; g -= 32768; }
        else { src = pa.c2; dst = pa.f2; g -= 98304; }
        const int l = g & 63;
        const int fr = g >> 6;
        const int t = fr >> 2, ks = (fr >> 1) & 1, pln = fr & 1;
        const int e = t * 16 + (l & 15);
        const int d0 = ks * 32 + (l >> 4) * 8;
        const float* s = src + (size_t)e * 64 + d0;
        union { unsigned short o[8]; u16x8 v; } U;
        #pragma unroll
        for (int j = 0; j < 8; ++j) {
            const float v = s[j];
            const unsigned u = __float_as_uint(v);
            const unsigned r = u + (0x7fffu + ((u >> 16) & 1u));
            if (pln == 0) {
                U.o[j] = (unsigned short)(r >> 16);
            } else {
                const float rem = v - __uint_as_float(r & 0xffff0000u);
                const unsigned lu = __float_as_uint(rem);
                U.o[j] = (unsigned short)((lu + (0x7fffu + ((lu >> 16) & 1u))) >> 16);
            }
        }
        *(u16x8*)(dst + (size_t)g * 8) = U.v;
    } else if (bid < 2568) {
        const int gid = (bid - 1320) * 256 + tid;
        int seg = 0;
        #pragma unroll 1
        for (int i = 0; i < 17; ++i)
            if (gid >= pa.wa.start[seg + 1]) seg++;
        const int s = gid - pa.wa.start[seg];
        const int l = s & 63, fr = s >> 6;
        const int kl = pa.wa.kslog[seg];
        const int pln = fr & 1;
        const int ks = (fr >> 1) & ((1 << kl) - 1);
        const int nt = fr >> (1 + kl);
        const int K = 32 << kl;
        const int n = nt * 16 + (l & 15);
        const int d0 = ks * 32 + (l >> 4) * 8;
        const float* sp = pa.wa.src[seg] + (size_t)n * K + d0;
        union { unsigned short o[8]; u16x8 v; } U;
        #pragma unroll
        for (int j = 0; j < 8; ++j) {
            const float v = sp[j];
            const unsigned u = __float_as_uint(v);
            const unsigned r = u + (0x7fffu + ((u >> 16) & 1u));
            if (pln == 0) {
                U.o[j] = (unsigned short)(r >> 16);
            } else {
                const float rem = v - __uint_as_float(r & 0xffff0000u);
                const unsigned lu = __float_as_uint(rem);
                U.o[j] = (unsigned short)((lu + (0x7fffu + ((lu >> 16) & 1u))) >> 16);
            }
        }
        *(u16x8*)(pa.wa.dst[seg] + (size_t)s * 8) = U.v;
    } else {
        const int j2 = bid - 2568;
        float* o = shm;
        float* v = shm + 4096;
        const float* wv = pa.iw[j2] + 128 * 64;
        const float* ow = pa.ow[j2];
        for (int t = tid; t < 4096; t += 256) { o[t] = ow[t]; v[t] = wv[t]; }
        __syncthreads();
        unsigned short* wc = (unsigned short*)pa.wcomb[j2];
        for (int t = tid; t < 4096; t += 256) {
            const int j = t >> 6, i = t & 63;
            float s = 0.f;
            #pragma unroll
            for (int k = 0; k < 64; ++k) s += o[j * 64 + k] * v[k * 64 + i];
            const unsigned u = __float_as_uint(s);
            const unsigned r = u + (0x7fffu + ((u >> 16) & 1u));
            const unsigned short hi = (unsigned short)(r >> 16);
            const float rem = s - __uint_as_float(r & 0xffff0000u);
            const unsigned lu = __float_as_uint(rem);
            const unsigned short lo = (unsigned short)((lu + (0x7fffu + ((lu >> 16) & 1u))) >> 16);
            const int nt = j >> 4, ks = i >> 5;
            const int lsub = (j & 15) | (((i >> 3) & 3) << 4);
            const int e = i & 7;
            wc[(size_t)((nt * 2 + ks) * 2 + 0) * 512 + lsub * 8 + e] = hi;
            wc[(size_t)((nt * 2 + ks) * 2 + 1) * 512 + lsub * 8 + e] = lo;
        }
        if (tid < 64) {
            const int j = tid;
            const float* bv = pa.ib[j2] + 128;
            float s = pa.ob[j2][j];
            #pragma unroll
            for (int k = 0; k < 64; ++k) s += o[j * 64 + k] * bv[k];
            pa.bcomb[j2][j] = s;
        }
    }
}

// ---------------- gemmb10: round-8 data path, BK=64 ---------------------------
// AMODE: 0 = interleaved u32 A, 1 = fp32 A, 2 = compact u16-hi row-major A.
// OUTP:  0 = fp32, 1 = interleaved u32, 4 = compact u16-hi row-major.
struct GemmB {
    const void* A[3];
    const unsigned short* W[3];
    const float* bias[3];
    void* C[3];
};
template<int SPLIT, int BN, int AMODE, int OUTP>
__global__ __launch_bounds__(256) void gemmb10(
    GemmB g, int M, int N, int K, int relu)
{
    constexpr int NT = BN / 32;
    __shared__ unsigned Asm[2 * 64 * 36];   // u32 tiles; aliased as u16[64][72] for AMODE==2
    const int z = blockIdx.z;
    const void* Ap_ = g.A[z];
    const unsigned short* Wf = g.W[z];
    const float* bias = g.bias[z];
    void* Cp = g.C[z];
    const int tid = threadIdx.x;
    const int m0 = blockIdx.y << 6;
    const int n0 = blockIdx.x * BN;
    const int lane = tid & 63, wv = tid >> 6;
    const int wm = wv >> 1, wn = wv & 1;
    const int q = lane >> 4, c16 = lane & 15;
    const int nk = K >> 5;
    const int nk2 = K >> 6;

    f32x4 acc[2][NT] = {};

    uint4 rA[4];
    auto ldA = [&](int k0) {
        if (AMODE == 2) {
            #pragma unroll
            for (int i = 0; i < 2; ++i) {
                const int c = tid + (i << 8);
                const int row = c >> 3, col8 = (c & 7) << 3;
                rA[i] = *(const uint4*)((const unsigned short*)Ap_ + (size_t)(m0 + row) * K + k0 + col8);
            }
        } else {
            #pragma unroll
            for (int i = 0; i < 4; ++i) {
                const int s = i >> 1;
                const int c = tid + ((i & 1) << 8);
                const int row = c >> 3, col = (c & 7) << 2;
                rA[i] = *(const uint4*)((const unsigned*)Ap_ + (size_t)(m0 + row) * K + k0 + s * 32 + col);
            }
        }
    };
    auto stA = [&]() {
        if (AMODE == 2) {
            unsigned short* A16 = (unsigned short*)Asm;
            #pragma unroll
            for (int i = 0; i < 2; ++i) {
                const int c = tid + (i << 8);
                const int row = c >> 3, col8 = (c & 7) << 3;
                *(uint4*)&A16[row * 72 + col8] = rA[i];
            }
        } else {
            #pragma unroll
            for (int i = 0; i < 4; ++i) {
                const int s = i >> 1;
                const int c = tid + ((i & 1) << 8);
                const int row = c >> 3, col = (c & 7) << 2;
                uint4 u;
                if (AMODE == 1) {
                    u.x = packbf(__uint_as_float(rA[i].x));
                    u.y = packbf(__uint_as_float(rA[i].y));
                    u.z = packbf(__uint_as_float(rA[i].z));
                    u.w = packbf(__uint_as_float(rA[i].w));
                } else {
                    u = rA[i];
                }
                *(uint4*)&Asm[s * 2304 + row * 36 + col] = u;
            }
        }
    };
    bf16x8 bh[NT], bl[NT];
    auto ldB = [&](int t) {
        #pragma unroll
        for (int nt = 0; nt < NT; ++nt) {
            const int tg = (n0 >> 4) + wn * NT + nt;
            const size_t fb = ((size_t)(tg * nk + t) * 2) * 512 + lane * 8;
            bh[nt] = *(const bf16x8*)(Wf + fb);
            if (SPLIT) bl[nt] = *(const bf16x8*)(Wf + fb + 512);
        }
    };
    auto SUB = [&](int s) {
        bf16x8 ah[2], al[2];
        #pragma unroll
        for (int mt = 0; mt < 2; ++mt) {
            const int r = wm * 32 + mt * 16 + c16;
            if (AMODE == 2) {
                const unsigned short* A16 = (const unsigned short*)Asm;
                ah[mt] = *(const bf16x8*)&A16[r * 72 + s * 32 + q * 8];
            } else {
                const int b = s * 2304 + r * 36 + q * 8;
                unpack8(*(const uint4*)&Asm[b], *(const uint4*)&Asm[b + 4], ah[mt], al[mt]);
            }
        }
        #pragma unroll
        for (int nt = 0; nt < NT; ++nt)
            #pragma unroll
            for (int mt = 0; mt < 2; ++mt) {
                acc[mt][nt] = __builtin_amdgcn_mfma_f32_16x16x32_bf16(ah[mt], bh[nt], acc[mt][nt], 0, 0, 0);
                if (SPLIT) {
                    acc[mt][nt] = __builtin_amdgcn_mfma_f32_16x16x32_bf16(ah[mt], bl[nt], acc[mt][nt], 0, 0, 0);
                    acc[mt][nt] = __builtin_amdgcn_mfma_f32_16x16x32_bf16(al[mt], bh[nt], acc[mt][nt], 0, 0, 0);
                }
            }
    };

    ldA(0);
    ldB(0);

    #pragma unroll 1
    for (int t2 = 0; t2 < nk2; ++t2) {
        __syncthreads();
        stA();
        if (t2 + 1 < nk2) ldA((t2 + 1) << 6);
        __syncthreads();
        SUB(0);
        ldB(2 * t2 + 1);
        SUB(1);
        if (t2 + 1 < nk2) ldB(2 * t2 + 2);
    }

    #pragma unroll
    for (int nt = 0; nt < NT; ++nt) {
        const int gcol = n0 + wn * (BN / 2) + nt * 16 + c16;
        const float bb = bias[gcol];
        #pragma unroll
        for (int mt = 0; mt < 2; ++mt)
            #pragma unroll
            for (int r = 0; r < 4; ++r) {
                const int grow = m0 + wm * 32 + mt * 16 + q * 4 + r;
                float v = acc[mt][nt][r] + bb;
                if (relu) v = fmaxf(v, 0.f);
                if (OUTP == 1) {
                    ((unsigned*)Cp)[(size_t)grow * N + gcol] = packbf(v);
                } else if (OUTP == 4) {
                    const unsigned uu = __float_as_uint(v);
                    const unsigned rn = uu + (0x7fffu + ((uu >> 16) & 1u));
                    ((unsigned short*)Cp)[(size_t)grow * N + gcol] = (unsigned short)(rn >> 16);
                } else {
                    ((float*)Cp)[(size_t)grow * N + gcol] = v;
                }
            }
    }
}

// ---------------- VQ sweep v2 ----------------
struct VqB2 {
    const unsigned* zep[10];
    const unsigned short* cbf[10];
    const float* cbn[10];
    int e_base[10];
};
__global__ __launch_bounds__(256) void vq_sweep2(
    VqB2 vb, float* __restrict__ bdo, int* __restrict__ bio)
{
    const int tid = threadIdx.x;
    const int lane = tid & 63, wv = tid >> 6;
    const int q = lane >> 4, c16 = lane & 15;
    const int chunk = blockIdx.y;
    const int s0 = blockIdx.x * 128 + wv * 32;
    const unsigned* zep = vb.zep[chunk];
    const int e_base = vb.e_base[chunk];
    const unsigned short* lbase =
        vb.cbf[chunk] + (size_t)(e_base >> 4) * 2048 + lane * 8;
    const float* cbn = vb.cbn[chunk] + e_base;

    bf16x8 ah[2][2], al[2][2];
    #pragma unroll
    for (int mt = 0; mt < 2; ++mt)
        #pragma unroll
        for (int ks = 0; ks < 2; ++ks) {
            const size_t a = (size_t)(s0 + mt * 16 + c16) * 64 + ks * 32 + q * 8;
            unpack8(*(const uint4*)(zep + a), *(const uint4*)(zep + a + 4),
                    ah[mt][ks], al[mt][ks]);
        }

    float bs[2][4];
    int   bi[2][4];
    #pragma unroll
    for (int mt = 0; mt < 2; ++mt)
        #pragma unroll
        for (int r = 0; r < 4; ++r) { bs[mt][r] = -3.4e38f; bi[mt][r] = 0x7fffffff; }

    auto ldT = [&](int t, bf16x8& b00, bf16x8& b01, bf16x8& b10, bf16x8& b11,
                   float& nn) {
        const unsigned short* p = lbase + (size_t)t * 2048;
        b00 = *(const bf16x8*)(p);
        b01 = *(const bf16x8*)(p + 512);
        b10 = *(const bf16x8*)(p + 1024);
        b11 = *(const bf16x8*)(p + 1536);
        nn = cbn[t * 16 + c16];
    };
    auto PROC = [&](const bf16x8& b00, const bf16x8& b01, const bf16x8& b10,
                    const bf16x8& b11, float nn, int t) {
        const float seed = -0.5f * nn;
        f32x4 a0 = {seed, seed, seed, seed};
        f32x4 a1 = a0;
        a0 = __builtin_amdgcn_mfma_f32_16x16x32_bf16(ah[0][0], b00, a0, 0, 0, 0);
        a1 = __builtin_amdgcn_mfma_f32_16x16x32_bf16(ah[1][0], b00, a1, 0, 0, 0);
        a0 = __builtin_amdgcn_mfma_f32_16x16x32_bf16(ah[0][0], b01, a0, 0, 0, 0);
        a1 = __builtin_amdgcn_mfma_f32_16x16x32_bf16(ah[1][0], b01, a1, 0, 0, 0);
        a0 = __builtin_amdgcn_mfma_f32_16x16x32_bf16(al[0][0], b00, a0, 0, 0, 0);
        a1 = __builtin_amdgcn_mfma_f32_16x16x32_bf16(al[1][0], b00, a1, 0, 0, 0);
        a0 = __builtin_amdgcn_mfma_f32_16x16x32_bf16(ah[0][1], b10, a0, 0, 0, 0);
        a1 = __builtin_amdgcn_mfma_f32_16x16x32_bf16(ah[1][1], b10, a1, 0, 0, 0);
        a0 = __builtin_amdgcn_mfma_f32_16x16x32_bf16(ah[0][1], b11, a0, 0, 0, 0);
        a1 = __builtin_amdgcn_mfma_f32_16x16x32_bf16(ah[1][1], b11, a1, 0, 0, 0);
        a0 = __builtin_amdgcn_mfma_f32_16x16x32_bf16(al[0][1], b10, a0, 0, 0, 0);
        a1 = __builtin_amdgcn_mfma_f32_16x16x32_bf16(al[1][1], b10, a1, 0, 0, 0);
        const int eidx = e_base + t * 16 + c16;
        #pragma unroll
        for (int r = 0; r < 4; ++r) {
            const float v0 = a0[r];
            if (v0 > bs[0][r]) { bs[0][r] = v0; bi[0][r] = eidx; }
            const float v1 = a1[r];
            if (v1 > bs[1][r]) { bs[1][r] = v1; bi[1][r] = eidx; }
        }
    };

    bf16x8 A00, A01, A10, A11, B00, B01, B10, B11;
    float nA, nB;
    ldT(0, A00, A01, A10, A11, nA);
    #pragma unroll 1
    for (int t = 0; t < 64; t += 2) {
        ldT(t + 1, B00, B01, B10, B11, nB);
        PROC(A00, A01, A10, A11, nA, t);
        if (t + 2 < 64) ldT(t + 2, A00, A01, A10, A11, nA);
        PROC(B00, B01, B10, B11, nB, t + 1);
    }

    #pragma unroll
    for (int off = 1; off < 16; off <<= 1)
        #pragma unroll
        for (int mt = 0; mt < 2; ++mt)
            #pragma unroll
            for (int r = 0; r < 4; ++r) {
                const float od = __shfl_xor(bs[mt][r], off, 64);
                const int   oi = __shfl_xor(bi[mt][r], off, 64);
                if (od > bs[mt][r] || (od == bs[mt][r] && oi < bi[mt][r])) {
                    bs[mt][r] = od; bi[mt][r] = oi;
                }
            }
    if (c16 == 0) {
        #pragma unroll
        for (int mt = 0; mt < 2; ++mt)
            #pragma unroll
            for (int r = 0; r < 4; ++r) {
                const int row = s0 + mt * 16 + q * 4 + r;
                bdo[(size_t)chunk * BSZ + row] = -2.0f * bs[mt][r];
                bio[(size_t)chunk * BSZ + row] = bi[mt][r];
            }
    }
}

// ---------------- merge chunks + gather zq planes ----------------
__global__ __launch_bounds__(256) void merge_gather_b(
    const float* __restrict__ bd, const int* __restrict__ bi,
    const unsigned* __restrict__ cb0, const unsigned* __restrict__ cb1,
    const unsigned* __restrict__ cb2, unsigned* __restrict__ zq_all)
{
    const int gid = blockIdx.x * 256 + threadIdx.x;
    const int l = gid / (BSZ * 64);
    const int r = gid - l * (BSZ * 64);
    const int s = r >> 6, d = r & 63;
    const int c0 = (l == 0) ? 0 : (l == 1 ? 2 : 6);
    const int c1 = (l == 0) ? 2 : (l == 1 ? 6 : 10);
    float best = bd[(size_t)c0 * BSZ + s];
    int   idx  = bi[(size_t)c0 * BSZ + s];
    for (int c = c0 + 1; c < c1; ++c) {
        const float dd = bd[(size_t)c * BSZ + s];
        const int   ii = bi[(size_t)c * BSZ + s];
        if (dd < best || (dd == best && ii < idx)) { best = dd; idx = ii; }
    }
    const unsigned* cb = (l == 0) ? cb0 : (l == 1 ? cb1 : cb2);
    zq_all[gid] = cb[(size_t)idx * 64 + d];
}

// ---------------- batched losses ----------------
__global__ __launch_bounds__(256) void loss_b(
    const unsigned* __restrict__ zep0, const unsigned* __restrict__ zq0,
    const unsigned* __restrict__ attb, float* __restrict__ vq_out,
    float* __restrict__ commit_out, float inv)
{
    const int l = blockIdx.z;
    const unsigned* ze = zep0 + (size_t)l * BSZ * 64;
    const unsigned* zq = zq0 + (size_t)l * BSZ * 64;
    const unsigned* at = (l > 0) ? attb + (size_t)(l - 1) * BSZ * 64 : nullptr;
    float cs = 0.f, vs = 0.f;
    for (int t = blockIdx.x * 256 + threadIdx.x; t < BSZ * 64; t += gridDim.x * 256) {
        const float e = unpackf(ze[t]);
        const float qv = unpackf(zq[t]);
        const float dc = e - qv;
        cs += dc * dc;
        const float za = at ? (e + unpackf(at[t])) : e;
        const float dv = qv - za;
        vs += dv * dv;
    }
    #pragma unroll
    for (int off = 32; off; off >>= 1) {
        cs += __shfl_down(cs, off, 64);
        vs += __shfl_down(vs, off, 64);
    }
    __shared__ float sc[4], sv[4];
    const int lane = threadIdx.x & 63, w = threadIdx.x >> 6;
    if (lane == 0) { sc[w] = cs; sv[w] = vs; }
    __syncthreads();
    if (threadIdx.x == 0) {
        atomicAdd(commit_out, (sc[0] + sc[1] + sc[2] + sc[3]) * inv);
        atomicAdd(vq_out, (sv[0] + sv[1] + sv[2] + sv[3]) * inv);
    }
}

extern "C" void kernel_launch(void* const* d_in, const int* in_sizes, int n_in,
                              void* d_out, int out_size, void* d_ws, size_t ws_size,
                              hipStream_t stream)
{
    const int CB_SIZES[3] = {2048, 4096, 4096};

    // ---- workspace layout (u32 units) ----
    unsigned* H1   = (unsigned*)d_ws;                  // 3 * B*256
    unsigned* H2   = H1 + (size_t)3 * BSZ * 256;       // 3 * B*256
    unsigned* ZEP  = H2 + (size_t)3 * BSZ * 256;       // 3 * B*64
    unsigned* ZQ   = ZEP + (size_t)3 * BSZ * 64;       // 3 * B*64
    unsigned* ATT  = ZQ + (size_t)3 * BSZ * 64;        // 2 * B*64
    float* cbn     = (float*)(ATT + (size_t)2 * BSZ * 64);  // 10240
    float* bd      = cbn + 10240;                      // 10 * BSZ
    int*   bi      = (int*)(bd + 10 * BSZ);            // 10 * BSZ
    unsigned* wcb  = (unsigned*)(bi + 10 * BSZ);       // 2*4096 fragged wcomb
    float* bcomb   = (float*)(wcb + 2 * 4096);         // 2*64
    unsigned* wp   = (unsigned*)(bcomb + 128);         // codebook interleaved planes

    float* out = (float*)d_out;
    float* vq_loss = out + (size_t)3 * BSZ * 512;
    float* commit  = vq_loss + 1;
    hipMemsetAsync(vq_loss, 0, 2 * sizeof(float), stream);

    // ---- merged preprocessing descriptor ----
    PrepAll pall;
    int pos = 0;
    const unsigned* cbp[3];
    for (int l = 0; l < 3; ++l) {
        pall.psrc[l] = (const float*)d_in[3 + 13 * l + 12];
        pall.pdst[l] = wp + pos;
        pall.pstart[l] = pos;
        cbp[l] = wp + pos;
        pos += CB_SIZES[l] * 64;
    }
    pall.pstart[3] = pos;   // 655360

    unsigned short* cbf0 = (unsigned short*)(wp + pos);
    unsigned short* cbf1 = cbf0 + (size_t)2048 * 128;
    unsigned short* cbf2 = cbf1 + (size_t)4096 * 128;
    unsigned short* wfr = (unsigned short*)(wp + pos + 655360);

    pall.c0 = (const float*)d_in[15];
    pall.c1 = (const float*)d_in[28];
    pall.c2 = (const float*)d_in[41];
    pall.cbn = cbn;
    pall.f0 = cbf0; pall.f1 = cbf1; pall.f2 = cbf2;

    int fpos = 0, wslot = 0;
    const unsigned short* wfp[3][6];
    auto addw = [&](const float* src, int Nn, int Kk, int kl) -> const unsigned short* {
        pall.wa.src[wslot] = src; pall.wa.dst[wslot] = wfr + (size_t)fpos * 8;
        pall.wa.start[wslot] = fpos; pall.wa.kslog[wslot] = kl;
        fpos += Nn * Kk / 4; wslot++;
        return pall.wa.dst[wslot - 1];
    };
    for (int l = 0; l < 3; ++l) {
        const int base = 3 + 13 * l;
        wfp[l][0] = addw((const float*)d_in[base + 0], 256, 512, 4);
        wfp[l][1] = addw((const float*)d_in[base + 2], 256, 256, 3);
        wfp[l][2] = addw((const float*)d_in[base + 4], 64, 256, 3);
        wfp[l][3] = addw((const float*)d_in[base + 6], 256, 64, 1);
        wfp[l][4] = addw((const float*)d_in[base + 8], 256, 256, 3);
        wfp[l][5] = addw((const float*)d_in[base + 10], 512, 256, 3);
    }
    pall.wa.start[18] = fpos;   // 319488 -> 1248 blocks

    for (int j = 0; j < 2; ++j) {
        pall.iw[j] = (const float*)d_in[42 + 4 * j];
        pall.ib[j] = (const float*)d_in[42 + 4 * j + 1];
        pall.ow[j] = (const float*)d_in[42 + 4 * j + 2];
        pall.ob[j] = (const float*)d_in[42 + 4 * j + 3];
        pall.wcomb[j] = wcb + j * 4096;
        pall.bcomb[j] = bcomb + j * 64;
    }

    hipLaunchKernelGGL(prep_all, dim3(2570), dim3(256), 0, stream, pall);

    // ---- encoders (unchanged: split needs both planes) ----
    GemmB g;
    for (int l = 0; l < 3; ++l) {
        g.A[l] = d_in[l]; g.W[l] = wfp[l][0];
        g.bias[l] = (const float*)d_in[3 + 13 * l + 1];
        g.C[l] = H1 + (size_t)l * BSZ * 256;
    }
    hipLaunchKernelGGL((gemmb10<1, 128, 1, 1>), dim3(2, 256, 3), dim3(256), 0, stream,
                       g, BSZ, 256, 512, 1);
    for (int l = 0; l < 3; ++l) {
        g.A[l] = H1 + (size_t)l * BSZ * 256; g.W[l] = wfp[l][1];
        g.bias[l] = (const float*)d_in[3 + 13 * l + 3];
        g.C[l] = H2 + (size_t)l * BSZ * 256;
    }
    hipLaunchKernelGGL((gemmb10<1, 128, 0, 1>), dim3(2, 256, 3), dim3(256), 0, stream,
                       g, BSZ, 256, 256, 1);
    for (int l = 0; l < 3; ++l) {
        g.A[l] = H2 + (size_t)l * BSZ * 256; g.W[l] = wfp[l][2];
        g.bias[l] = (const float*)d_in[3 + 13 * l + 5];
        g.C[l] = ZEP + (size_t)l * BSZ * 64;
    }
    hipLaunchKernelGGL((gemmb10<1, 64, 0, 1>), dim3(1, 256, 3), dim3(256), 0, stream,
                       g, BSZ, 64, 256, 0);

    // ---- VQ ----
    VqB2 vb;
    {
        const unsigned short* cbfl[3] = {cbf0, cbf1, cbf2};
        int c = 0;
        for (int l = 0; l < 3; ++l) {
            const int nch = CB_SIZES[l] / 1024;
            const int cb_off = (l == 0) ? 0 : (l == 1 ? 2048 : 6144);
            for (int k = 0; k < nch; ++k, ++c) {
                vb.zep[c] = ZEP + (size_t)l * BSZ * 64;
                vb.cbf[c] = cbfl[l];
                vb.cbn[c] = cbn + cb_off;
                vb.e_base[c] = k * 1024;
            }
        }
    }
    hipLaunchKernelGGL(vq_sweep2, dim3(BSZ / 128, 10), dim3(256), 0, stream, vb, bd, bi);
    hipLaunchKernelGGL(merge_gather_b, dim3(3 * BSZ * 64 / 256), dim3(256), 0, stream,
                       bd, bi, cbp[0], cbp[1], cbp[2], ZQ);

    // ---- folded attention ----
    for (int j = 0; j < 2; ++j) {
        g.A[j] = ZQ + (size_t)j * BSZ * 64;
        g.W[j] = (const unsigned short*)(wcb + j * 4096);
        g.bias[j] = bcomb + j * 64;
        g.C[j] = ATT + (size_t)j * BSZ * 64;
    }
    g.A[2] = g.A[1]; g.W[2] = g.W[1]; g.bias[2] = g.bias[1]; g.C[2] = g.C[1];
    hipLaunchKernelGGL((gemmb10<0, 64, 0, 1>), dim3(1, 256, 2), dim3(256), 0, stream,
                       g, BSZ, 64, 64, 0);

    // ---- losses ----
    hipLaunchKernelGGL(loss_b, dim3(256, 1, 3), dim3(256), 0, stream,
                       ZEP, ZQ, ATT, vq_loss, commit, 1.0f / (float)(BSZ * 64));

    // ---- decoders: compact u16-hi intermediates (lo plane was dead) ----
    for (int l = 0; l < 3; ++l) {
        g.A[l] = ZQ + (size_t)l * BSZ * 64; g.W[l] = wfp[l][3];
        g.bias[l] = (const float*)d_in[3 + 13 * l + 7];
        g.C[l] = (unsigned short*)H1 + (size_t)l * BSZ * 256;
    }
    hipLaunchKernelGGL((gemmb10<0, 128, 0, 4>), dim3(2, 256, 3), dim3(256), 0, stream,
                       g, BSZ, 256, 64, 1);
    for (int l = 0; l < 3; ++l) {
        g.A[l] = (unsigned short*)H1 + (size_t)l * BSZ * 256; g.W[l] = wfp[l][4];
        g.bias[l] = (const float*)d_in[3 + 13 * l + 9];
        g.C[l] = (unsigned short*)H2 + (size_t)l * BSZ * 256;
    }
    hipLaunchKernelGGL((gemmb10<0, 128, 2, 4>), dim3(2, 256, 3), dim3(256), 0, stream,
                       g, BSZ, 256, 256, 1);
    for (int l = 0; l < 3; ++l) {
        g.A[l] = (unsigned short*)H2 + (size_t)l * BSZ * 256; g.W[l] = wfp[l][5];
        g.bias[l] = (const float*)d_in[3 + 13 * l + 11];
        g.C[l] = out + (size_t)l * BSZ * 512;
    }
    hipLaunchKernelGGL((gemmb10<0, 128, 2, 0>), dim3(4, 256, 3), dim3(256), 0, stream,
                       g, BSZ, 512, 256, 0);
}

// Round 17
// 540.908 us; speedup vs baseline: 1.0275x; 1.0275x over previous
//
#include <hip/hip_runtime.h>

#define BSZ 16384

typedef __attribute__((ext_vector_type(8))) short bf16x8;
typedef __attribute__((ext_vector_type(4))) float f32x4;
typedef __attribute__((ext_vector_type(8))) unsigned short u16x8;

// pack fp32 -> interleaved (hi bf16 | lo bf16 << 16); hi+lo ~= x within 2^-16 rel
__device__ inline unsigned packbf(float v) {
    unsigned u = __float_as_uint(v);
    unsigned r = u + (0x7fffu + ((u >> 16) & 1u));
    unsigned hi = r >> 16;
    float rem = v - __uint_as_float(r & 0xffff0000u);
    unsigned lu = __float_as_uint(rem);
    unsigned lo = (lu + (0x7fffu + ((lu >> 16) & 1u))) >> 16;
    return hi | (lo << 16);
}
__device__ inline float unpackf(unsigned u) {
    return __uint_as_float(u << 16) + __uint_as_float(u & 0xffff0000u);
}
// 8 interleaved elems (two uint4) -> hi-plane and lo-plane bf16x8 frags
__device__ inline void unpack8(const uint4 p0, const uint4 p1, bf16x8& hi, bf16x8& lo) {
    union { unsigned u[4]; bf16x8 v; } H, L;
    H.u[0] = __builtin_amdgcn_perm(p0.y, p0.x, 0x05040100u);
    H.u[1] = __builtin_amdgcn_perm(p0.w, p0.z, 0x05040100u);
    H.u[2] = __builtin_amdgcn_perm(p1.y, p1.x, 0x05040100u);
    H.u[3] = __builtin_amdgcn_perm(p1.w, p1.z, 0x05040100u);
    L.u[0] = __builtin_amdgcn_perm(p0.y, p0.x, 0x07060302u);
    L.u[1] = __builtin_amdgcn_perm(p0.w, p0.z, 0x07060302u);
    L.u[2] = __builtin_amdgcn_perm(p1.y, p1.x, 0x07060302u);
    L.u[3] = __builtin_amdgcn_perm(p1.w, p1.z, 0x07060302u);
    hi = H.v; lo = L.v;
}

// ---------------- merged preprocessing kernel -----------------------------
struct WFA {
    const float* src[18];
    unsigned short* dst[18];
    int start[19];
    int kslog[18];
};
struct PrepAll {
    const float* psrc[3]; unsigned* pdst[3]; int pstart[4];
    const float* c0; const float* c1; const float* c2;
    float* cbn;
    unsigned short* f0; unsigned short* f1; unsigned short* f2;
    WFA wa;
    const float* iw[2]; const float* ib[2];
    const float* ow[2]; const float* ob[2];
    unsigned* wcomb[2]; float* bcomb[2];
};
__global__ __launch_bounds__(256) void prep_all(PrepAll pa) {
    __shared__ float shm[8192];
    const int bid = blockIdx.x;
    const int tid = threadIdx.x;
    if (bid < 640) {
        const int base = bid << 10;
        int seg = 0;
        if (base >= pa.pstart[1]) seg = 1;
        if (base >= pa.pstart[2]) seg = 2;
        const int off = base - pa.pstart[seg] + (tid << 2);
        const float4 v = *(const float4*)(pa.psrc[seg] + off);
        uint4 u;
        u.x = packbf(v.x); u.y = packbf(v.y); u.z = packbf(v.z); u.w = packbf(v.w);
        *(uint4*)(pa.pdst[seg] + off) = u;
    } else if (bid < 680) {
        const int r = (bid - 640) * 256 + tid;
        const float* src; int off;
        if (r < 2048) { src = pa.c0; off = r; }
        else if (r < 6144) { src = pa.c1; off = r - 2048; }
        else { src = pa.c2; off = r - 6144; }
        const float4* p = (const float4*)(src + (size_t)off * 64);
        float s = 0.f;
        #pragma unroll
        for (int c = 0; c < 16; ++c) {
            float4 v = p[c];
            s += v.x * v.x + v.y * v.y + v.z * v.z + v.w * v.w;
        }
        pa.cbn[r] = s;
    } else if (bid < 1320) {
        int g = (bid - 680) * 256 + tid;
        const float* src; unsigned short* dst;
        if (g < 32768) { src = pa.c0; dst = pa.f0; }
        else if (g < 98304) { src = pa.c1; dst = pa.f1; g -= 32768; }
        else { src = pa.c2; dst = pa.f2; g -= 98304; }
        const int l = g & 63;
        const int fr = g >> 6;
        const int t = fr >> 2, ks = (fr >> 1) & 1, pln = fr & 1;
        const int e = t * 16 + (l & 15);
        const int d0 = ks * 32 + (l >> 4) * 8;
        const float* s = src + (size_t)e * 64 + d0;
        union { unsigned short o[8]; u16x8 v; } U;
        #pragma unroll
        for (int j = 0; j < 8; ++j) {
            const float v = s[j];
            const unsigned u = __float_as_uint(v);
            const unsigned r = u + (0x7fffu + ((u >> 16) & 1u));
            if (pln == 0) {
                U.o[j] = (unsigned short)(r >> 16);
            } else {
                const float rem = v - __uint_as_float(r & 0xffff0000u);
                const unsigned lu = __float_as_uint(rem);
                U.o[j] = (unsigned short)((lu + (0x7fffu + ((lu >> 16) & 1u))) >> 16);
            }
        }
        *(u16x8*)(dst + (size_t)g * 8) = U.v;
    } else if (bid < 2568) {
        const int gid = (bid - 1320) * 256 + tid;
        int seg = 0;
        #pragma unroll 1
        for (int i = 0; i < 17; ++i)
            if (gid >= pa.wa.start[seg + 1]) seg++;
        const int s = gid - pa.wa.start[seg];
        const int l = s & 63, fr = s >> 6;
        const int kl = pa.wa.kslog[seg];
        const int pln = fr & 1;
        const int ks = (fr >> 1) & ((1 << kl) - 1);
        const int nt = fr >> (1 + kl);
        const int K = 32 << kl;
        const int n = nt * 16 + (l & 15);
        const int d0 = ks * 32 + (l >> 4) * 8;
        const float* sp = pa.wa.src[seg] + (size_t)n * K + d0;
        union { unsigned short o[8]; u16x8 v; } U;
        #pragma unroll
        for (int j = 0; j < 8; ++j) {
            const float v = sp[j];
            const unsigned u = __float_as_uint(v);
            const unsigned r = u + (0x7fffu + ((u >> 16) & 1u));
            if (pln == 0) {
                U.o[j] = (unsigned short)(r >> 16);
            } else {
                const float rem = v - __uint_as_float(r & 0xffff0000u);
                const unsigned lu = __float_as_uint(rem);
                U.o[j] = (unsigned short)((lu + (0x7fffu + ((lu >> 16) & 1u))) >> 16);
            }
        }
        *(u16x8*)(pa.wa.dst[seg] + (size_t)s * 8) = U.v;
    } else {
        const int j2 = bid - 2568;
        float* o = shm;
        float* v = shm + 4096;
        const float* wv = pa.iw[j2] + 128 * 64;
        const float* ow = pa.ow[j2];
        for (int t = tid; t < 4096; t += 256) { o[t] = ow[t]; v[t] = wv[t]; }
        __syncthreads();
        unsigned short* wc = (unsigned short*)pa.wcomb[j2];
        for (int t = tid; t < 4096; t += 256) {
            const int j = t >> 6, i = t & 63;
            float s = 0.f;
            #pragma unroll
            for (int k = 0; k < 64; ++k) s += o[j * 64 + k] * v[k * 64 + i];
            const unsigned u = __float_as_uint(s);
            const unsigned r = u + (0x7fffu + ((u >> 16) & 1u));
            const unsigned short hi = (unsigned short)(r >> 16);
            const float rem = s - __uint_as_float(r & 0xffff0000u);
            const unsigned lu = __float_as_uint(rem);
            const unsigned short lo = (unsigned short)((lu + (0x7fffu + ((lu >> 16) & 1u))) >> 16);
            const int nt = j >> 4, ks = i >> 5;
            const int lsub = (j & 15) | (((i >> 3) & 3) << 4);
            const int e = i & 7;
            wc[(size_t)((nt * 2 + ks) * 2 + 0) * 512 + lsub * 8 + e] = hi;
            wc[(size_t)((nt * 2 + ks) * 2 + 1) * 512 + lsub * 8 + e] = lo;
        }
        if (tid < 64) {
            const int j = tid;
            const float* bv = pa.ib[j2] + 128;
            float s = pa.ob[j2][j];
            #pragma unroll
            for (int k = 0; k < 64; ++k) s += o[j * 64 + k] * bv[k];
            pa.bcomb[j2][j] = s;
        }
    }
}

// ---------------- gemmb10: round-8 data path, BK=64 ---------------------------
// AMODE: 0 = interleaved u32 A, 1 = fp32 A. OUTP: 0 = fp32, 1 = interleaved u32.
struct GemmB {
    const void* A[3];
    const unsigned short* W[3];
    const float* bias[3];
    void* C[3];
};
template<int SPLIT, int BN, int AMODE, int OUTP>
__global__ __launch_bounds__(256) void gemmb10(
    GemmB g, int M, int N, int K, int relu)
{
    constexpr int NT = BN / 32;
    __shared__ unsigned Asm[2 * 64 * 36];   // two 64x32 sub-tiles, stride 36
    const int z = blockIdx.z;
    const void* Ap_ = g.A[z];
    const unsigned short* Wf = g.W[z];
    const float* bias = g.bias[z];
    void* Cp = g.C[z];
    const int tid = threadIdx.x;
    const int m0 = blockIdx.y << 6;
    const int n0 = blockIdx.x * BN;
    const int lane = tid & 63, wv = tid >> 6;
    const int wm = wv >> 1, wn = wv & 1;
    const int q = lane >> 4, c16 = lane & 15;
    const int nk = K >> 5;
    const int nk2 = K >> 6;

    f32x4 acc[2][NT] = {};

    uint4 rA[4];
    auto ldA = [&](int k0) {
        #pragma unroll
        for (int i = 0; i < 4; ++i) {
            const int s = i >> 1;
            const int c = tid + ((i & 1) << 8);
            const int row = c >> 3, col = (c & 7) << 2;
            rA[i] = *(const uint4*)((const unsigned*)Ap_ + (size_t)(m0 + row) * K + k0 + s * 32 + col);
        }
    };
    auto stA = [&]() {
        #pragma unroll
        for (int i = 0; i < 4; ++i) {
            const int s = i >> 1;
            const int c = tid + ((i & 1) << 8);
            const int row = c >> 3, col = (c & 7) << 2;
            uint4 u;
            if (AMODE == 1) {
                u.x = packbf(__uint_as_float(rA[i].x));
                u.y = packbf(__uint_as_float(rA[i].y));
                u.z = packbf(__uint_as_float(rA[i].z));
                u.w = packbf(__uint_as_float(rA[i].w));
            } else {
                u = rA[i];
            }
            *(uint4*)&Asm[s * 2304 + row * 36 + col] = u;
        }
    };
    bf16x8 bh[NT], bl[NT];
    auto ldB = [&](int t) {
        #pragma unroll
        for (int nt = 0; nt < NT; ++nt) {
            const int tg = (n0 >> 4) + wn * NT + nt;
            const size_t fb = ((size_t)(tg * nk + t) * 2) * 512 + lane * 8;
            bh[nt] = *(const bf16x8*)(Wf + fb);
            if (SPLIT) bl[nt] = *(const bf16x8*)(Wf + fb + 512);
        }
    };
    auto SUB = [&](int s) {
        bf16x8 ah[2], al[2];
        #pragma unroll
        for (int mt = 0; mt < 2; ++mt) {
            const int b = s * 2304 + (wm * 32 + mt * 16 + c16) * 36 + q * 8;
            unpack8(*(const uint4*)&Asm[b], *(const uint4*)&Asm[b + 4], ah[mt], al[mt]);
        }
        #pragma unroll
        for (int nt = 0; nt < NT; ++nt)
            #pragma unroll
            for (int mt = 0; mt < 2; ++mt) {
                acc[mt][nt] = __builtin_amdgcn_mfma_f32_16x16x32_bf16(ah[mt], bh[nt], acc[mt][nt], 0, 0, 0);
                if (SPLIT) {
                    acc[mt][nt] = __builtin_amdgcn_mfma_f32_16x16x32_bf16(ah[mt], bl[nt], acc[mt][nt], 0, 0, 0);
                    acc[mt][nt] = __builtin_amdgcn_mfma_f32_16x16x32_bf16(al[mt], bh[nt], acc[mt][nt], 0, 0, 0);
                }
            }
    };

    ldA(0);
    ldB(0);

    #pragma unroll 1
    for (int t2 = 0; t2 < nk2; ++t2) {
        __syncthreads();
        stA();
        if (t2 + 1 < nk2) ldA((t2 + 1) << 6);
        __syncthreads();
        SUB(0);
        ldB(2 * t2 + 1);
        SUB(1);
        if (t2 + 1 < nk2) ldB(2 * t2 + 2);
    }

    #pragma unroll
    for (int nt = 0; nt < NT; ++nt) {
        const int gcol = n0 + wn * (BN / 2) + nt * 16 + c16;
        const float bb = bias[gcol];
        #pragma unroll
        for (int mt = 0; mt < 2; ++mt)
            #pragma unroll
            for (int r = 0; r < 4; ++r) {
                const int grow = m0 + wm * 32 + mt * 16 + q * 4 + r;
                float v = acc[mt][nt][r] + bb;
                if (relu) v = fmaxf(v, 0.f);
                if (OUTP) ((unsigned*)Cp)[(size_t)grow * N + gcol] = packbf(v);
                else      ((float*)Cp)[(size_t)grow * N + gcol] = v;
            }
    }
}

// ---------------- VQ sweep v2 ----------------
struct VqB2 {
    const unsigned* zep[10];
    const unsigned short* cbf[10];
    const float* cbn[10];
    int e_base[10];
};
__global__ __launch_bounds__(256) void vq_sweep2(
    VqB2 vb, float* __restrict__ bdo, int* __restrict__ bio)
{
    const int tid = threadIdx.x;
    const int lane = tid & 63, wv = tid >> 6;
    const int q = lane >> 4, c16 = lane & 15;
    const int chunk = blockIdx.y;
    const int s0 = blockIdx.x * 128 + wv * 32;
    const unsigned* zep = vb.zep[chunk];
    const int e_base = vb.e_base[chunk];
    const unsigned short* lbase =
        vb.cbf[chunk] + (size_t)(e_base >> 4) * 2048 + lane * 8;
    const float* cbn = vb.cbn[chunk] + e_base;

    bf16x8 ah[2][2], al[2][2];
    #pragma unroll
    for (int mt = 0; mt < 2; ++mt)
        #pragma unroll
        for (int ks = 0; ks < 2; ++ks) {
            const size_t a = (size_t)(s0 + mt * 16 + c16) * 64 + ks * 32 + q * 8;
            unpack8(*(const uint4*)(zep + a), *(const uint4*)(zep + a + 4),
                    ah[mt][ks], al[mt][ks]);
        }

    float bs[2][4];
    int   bi[2][4];
    #pragma unroll
    for (int mt = 0; mt < 2; ++mt)
        #pragma unroll
        for (int r = 0; r < 4; ++r) { bs[mt][r] = -3.4e38f; bi[mt][r] = 0x7fffffff; }

    auto ldT = [&](int t, bf16x8& b00, bf16x8& b01, bf16x8& b10, bf16x8& b11,
                   float& nn) {
        const unsigned short* p = lbase + (size_t)t * 2048;
        b00 = *(const bf16x8*)(p);
        b01 = *(const bf16x8*)(p + 512);
        b10 = *(const bf16x8*)(p + 1024);
        b11 = *(const bf16x8*)(p + 1536);
        nn = cbn[t * 16 + c16];
    };
    auto PROC = [&](const bf16x8& b00, const bf16x8& b01, const bf16x8& b10,
                    const bf16x8& b11, float nn, int t) {
        const float seed = -0.5f * nn;
        f32x4 a0 = {seed, seed, seed, seed};
        f32x4 a1 = a0;
        a0 = __builtin_amdgcn_mfma_f32_16x16x32_bf16(ah[0][0], b00, a0, 0, 0, 0);
        a1 = __builtin_amdgcn_mfma_f32_16x16x32_bf16(ah[1][0], b00, a1, 0, 0, 0);
        a0 = __builtin_amdgcn_mfma_f32_16x16x32_bf16(ah[0][0], b01, a0, 0, 0, 0);
        a1 = __builtin_amdgcn_mfma_f32_16x16x32_bf16(ah[1][0], b01, a1, 0, 0, 0);
        a0 = __builtin_amdgcn_mfma_f32_16x16x32_bf16(al[0][0], b00, a0, 0, 0, 0);
        a1 = __builtin_amdgcn_mfma_f32_16x16x32_bf16(al[1][0], b00, a1, 0, 0, 0);
        a0 = __builtin_amdgcn_mfma_f32_16x16x32_bf16(ah[0][1], b10, a0, 0, 0, 0);
        a1 = __builtin_amdgcn_mfma_f32_16x16x32_bf16(ah[1][1], b10, a1, 0, 0, 0);
        a0 = __builtin_amdgcn_mfma_f32_16x16x32_bf16(ah[0][1], b11, a0, 0, 0, 0);
        a1 = __builtin_amdgcn_mfma_f32_16x16x32_bf16(ah[1][1], b11, a1, 0, 0, 0);
        a0 = __builtin_amdgcn_mfma_f32_16x16x32_bf16(al[0][1], b10, a0, 0, 0, 0);
        a1 = __builtin_amdgcn_mfma_f32_16x16x32_bf16(al[1][1], b10, a1, 0, 0, 0);
        const int eidx = e_base + t * 16 + c16;
        #pragma unroll
        for (int r = 0; r < 4; ++r) {
            const float v0 = a0[r];
            if (v0 > bs[0][r]) { bs[0][r] = v0; bi[0][r] = eidx; }
            const float v1 = a1[r];
            if (v1 > bs[1][r]) { bs[1][r] = v1; bi[1][r] = eidx; }
        }
    };

    bf16x8 A00, A01, A10, A11, B00, B01, B10, B11;
    float nA, nB;
    ldT(0, A00, A01, A10, A11, nA);
    #pragma unroll 1
    for (int t = 0; t < 64; t += 2) {
        ldT(t + 1, B00, B01, B10, B11, nB);
        PROC(A00, A01, A10, A11, nA, t);
        if (t + 2 < 64) ldT(t + 2, A00, A01, A10, A11, nA);
        PROC(B00, B01, B10, B11, nB, t + 1);
    }

    #pragma unroll
    for (int off = 1; off < 16; off <<= 1)
        #pragma unroll
        for (int mt = 0; mt < 2; ++mt)
            #pragma unroll
            for (int r = 0; r < 4; ++r) {
                const float od = __shfl_xor(bs[mt][r], off, 64);
                const int   oi = __shfl_xor(bi[mt][r], off, 64);
                if (od > bs[mt][r] || (od == bs[mt][r] && oi < bi[mt][r])) {
                    bs[mt][r] = od; bi[mt][r] = oi;
                }
            }
    if (c16 == 0) {
        #pragma unroll
        for (int mt = 0; mt < 2; ++mt)
            #pragma unroll
            for (int r = 0; r < 4; ++r) {
                const int row = s0 + mt * 16 + q * 4 + r;
                bdo[(size_t)chunk * BSZ + row] = -2.0f * bs[mt][r];
                bio[(size_t)chunk * BSZ + row] = bi[mt][r];
            }
    }
}

// ---------------- merge chunks + gather zq planes ----------------
__global__ __launch_bounds__(256) void merge_gather_b(
    const float* __restrict__ bd, const int* __restrict__ bi,
    const unsigned* __restrict__ cb0, const unsigned* __restrict__ cb1,
    const unsigned* __restrict__ cb2, unsigned* __restrict__ zq_all)
{
    const int gid = blockIdx.x * 256 + threadIdx.x;
    const int l = gid / (BSZ * 64);
    const int r = gid - l * (BSZ * 64);
    const int s = r >> 6, d = r & 63;
    const int c0 = (l == 0) ? 0 : (l == 1 ? 2 : 6);
    const int c1 = (l == 0) ? 2 : (l == 1 ? 6 : 10);
    float best = bd[(size_t)c0 * BSZ + s];
    int   idx  = bi[(size_t)c0 * BSZ + s];
    for (int c = c0 + 1; c < c1; ++c) {
        const float dd = bd[(size_t)c * BSZ + s];
        const int   ii = bi[(size_t)c * BSZ + s];
        if (dd < best || (dd == best && ii < idx)) { best = dd; idx = ii; }
    }
    const unsigned* cb = (l == 0) ? cb0 : (l == 1 ? cb1 : cb2);
    zq_all[gid] = cb[(size_t)idx * 64 + d];
}

// ---------------- batched losses ----------------
__global__ __launch_bounds__(256) void loss_b(
    const unsigned* __restrict__ zep0, const unsigned* __restrict__ zq0,
    const unsigned* __restrict__ attb, float* __restrict__ vq_out,
    float* __restrict__ commit_out, float inv)
{
    const int l = blockIdx.z;
    const unsigned* ze = zep0 + (size_t)l * BSZ * 64;
    const unsigned* zq = zq0 + (size_t)l * BSZ * 64;
    const unsigned* at = (l > 0) ? attb + (size_t)(l - 1) * BSZ * 64 : nullptr;
    float cs = 0.f, vs = 0.f;
    for (int t = blockIdx.x * 256 + threadIdx.x; t < BSZ * 64; t += gridDim.x * 256) {
        const float e = unpackf(ze[t]);
        const float qv = unpackf(zq[t]);
        const float dc = e - qv;
        cs += dc * dc;
        const float za = at ? (e + unpackf(at[t])) : e;
        const float dv = qv - za;
        vs += dv * dv;
    }
    #pragma unroll
    for (int off = 32; off; off >>= 1) {
        cs += __shfl_down(cs, off, 64);
        vs += __shfl_down(vs, off, 64);
    }
    __shared__ float sc[4], sv[4];
    const int lane = threadIdx.x & 63, w = threadIdx.x >> 6;
    if (lane == 0) { sc[w] = cs; sv[w] = vs; }
    __syncthreads();
    if (threadIdx.x == 0) {
        atomicAdd(commit_out, (sc[0] + sc[1] + sc[2] + sc[3]) * inv);
        atomicAdd(vq_out, (sv[0] + sv[1] + sv[2] + sv[3]) * inv);
    }
}

extern "C" void kernel_launch(void* const* d_in, const int* in_sizes, int n_in,
                              void* d_out, int out_size, void* d_ws, size_t ws_size,
                              hipStream_t stream)
{
    const int CB_SIZES[3] = {2048, 4096, 4096};

    // ---- workspace layout (u32 units) ----
    unsigned* H1   = (unsigned*)d_ws;                  // 3 * B*256
    unsigned* H2   = H1 + (size_t)3 * BSZ * 256;       // 3 * B*256
    unsigned* ZEP  = H2 + (size_t)3 * BSZ * 256;       // 3 * B*64
    unsigned* ZQ   = ZEP + (size_t)3 * BSZ * 64;       // 3 * B*64
    unsigned* ATT  = ZQ + (size_t)3 * BSZ * 64;        // 2 * B*64
    float* cbn     = (float*)(ATT + (size_t)2 * BSZ * 64);  // 10240
    float* bd      = cbn + 10240;                      // 10 * BSZ
    int*   bi      = (int*)(bd + 10 * BSZ);            // 10 * BSZ
    unsigned* wcb  = (unsigned*)(bi + 10 * BSZ);       // 2*4096 fragged wcomb
    float* bcomb   = (float*)(wcb + 2 * 4096);         // 2*64
    unsigned* wp   = (unsigned*)(bcomb + 128);         // codebook interleaved planes

    float* out = (float*)d_out;
    float* vq_loss = out + (size_t)3 * BSZ * 512;
    float* commit  = vq_loss + 1;
    hipMemsetAsync(vq_loss, 0, 2 * sizeof(float), stream);

    // ---- merged preprocessing descriptor ----
    PrepAll pall;
    int pos = 0;
    const unsigned* cbp[3];
    for (int l = 0; l < 3; ++l) {
        pall.psrc[l] = (const float*)d_in[3 + 13 * l + 12];
        pall.pdst[l] = wp + pos;
        pall.pstart[l] = pos;
        cbp[l] = wp + pos;
        pos += CB_SIZES[l] * 64;
    }
    pall.pstart[3] = pos;   // 655360

    unsigned short* cbf0 = (unsigned short*)(wp + pos);
    unsigned short* cbf1 = cbf0 + (size_t)2048 * 128;
    unsigned short* cbf2 = cbf1 + (size_t)4096 * 128;
    unsigned short* wfr = (unsigned short*)(wp + pos + 655360);

    pall.c0 = (const float*)d_in[15];
    pall.c1 = (const float*)d_in[28];
    pall.c2 = (const float*)d_in[41];
    pall.cbn = cbn;
    pall.f0 = cbf0; pall.f1 = cbf1; pall.f2 = cbf2;

    int fpos = 0, wslot = 0;
    const unsigned short* wfp[3][6];
    auto addw = [&](const float* src, int Nn, int Kk, int kl) -> const unsigned short* {
        pall.wa.src[wslot] = src; pall.wa.dst[wslot] = wfr + (size_t)fpos * 8;
        pall.wa.start[wslot] = fpos; pall.wa.kslog[wslot] = kl;
        fpos += Nn * Kk / 4; wslot++;
        return pall.wa.dst[wslot - 1];
    };
    for (int l = 0; l < 3; ++l) {
        const int base = 3 + 13 * l;
        wfp[l][0] = addw((const float*)d_in[base + 0], 256, 512, 4);
        wfp[l][1] = addw((const float*)d_in[base + 2], 256, 256, 3);
        wfp[l][2] = addw((const float*)d_in[base + 4], 64, 256, 3);
        wfp[l][3] = addw((const float*)d_in[base + 6], 256, 64, 1);
        wfp[l][4] = addw((const float*)d_in[base + 8], 256, 256, 3);
        wfp[l][5] = addw((const float*)d_in[base + 10], 512, 256, 3);
    }
    pall.wa.start[18] = fpos;   // 319488 -> 1248 blocks

    for (int j = 0; j < 2; ++j) {
        pall.iw[j] = (const float*)d_in[42 + 4 * j];
        pall.ib[j] = (const float*)d_in[42 + 4 * j + 1];
        pall.ow[j] = (const float*)d_in[42 + 4 * j + 2];
        pall.ob[j] = (const float*)d_in[42 + 4 * j + 3];
        pall.wcomb[j] = wcb + j * 4096;
        pall.bcomb[j] = bcomb + j * 64;
    }

    hipLaunchKernelGGL(prep_all, dim3(2570), dim3(256), 0, stream, pall);

    // ---- encoders ----
    GemmB g;
    for (int l = 0; l < 3; ++l) {
        g.A[l] = d_in[l]; g.W[l] = wfp[l][0];
        g.bias[l] = (const float*)d_in[3 + 13 * l + 1];
        g.C[l] = H1 + (size_t)l * BSZ * 256;
    }
    hipLaunchKernelGGL((gemmb10<1, 128, 1, 1>), dim3(2, 256, 3), dim3(256), 0, stream,
                       g, BSZ, 256, 512, 1);
    for (int l = 0; l < 3; ++l) {
        g.A[l] = H1 + (size_t)l * BSZ * 256; g.W[l] = wfp[l][1];
        g.bias[l] = (const float*)d_in[3 + 13 * l + 3];
        g.C[l] = H2 + (size_t)l * BSZ * 256;
    }
    hipLaunchKernelGGL((gemmb10<1, 128, 0, 1>), dim3(2, 256, 3), dim3(256), 0, stream,
                       g, BSZ, 256, 256, 1);
    for (int l = 0; l < 3; ++l) {
        g.A[l] = H2 + (size_t)l * BSZ * 256; g.W[l] = wfp[l][2];
        g.bias[l] = (const float*)d_in[3 + 13 * l + 5];
        g.C[l] = ZEP + (size_t)l * BSZ * 64;
    }
    hipLaunchKernelGGL((gemmb10<1, 64, 0, 1>), dim3(1, 256, 3), dim3(256), 0, stream,
                       g, BSZ, 64, 256, 0);

    // ---- VQ ----
    VqB2 vb;
    {
        const unsigned short* cbfl[3] = {cbf0, cbf1, cbf2};
        int c = 0;
        for (int l = 0; l < 3; ++l) {
            const int nch = CB_SIZES[l] / 1024;
            const int cb_off = (l == 0) ? 0 : (l == 1 ? 2048 : 6144);
            for (int k = 0; k < nch; ++k, ++c) {
                vb.zep[c] = ZEP + (size_t)l * BSZ * 64;
                vb.cbf[c] = cbfl[l];
                vb.cbn[c] = cbn + cb_off;
                vb.e_base[c] = k * 1024;
            }
        }
    }
    hipLaunchKernelGGL(vq_sweep2, dim3(BSZ / 128, 10), dim3(256), 0, stream, vb, bd, bi);
    hipLaunchKernelGGL(merge_gather_b, dim3(3 * BSZ * 64 / 256), dim3(256), 0, stream,
                       bd, bi, cbp[0], cbp[1], cbp[2], ZQ);

    // ---- folded attention ----
    for (int j = 0; j < 2; ++j) {
        g.A[j] = ZQ + (size_t)j * BSZ * 64;
        g.W[j] = (const unsigned short*)(wcb + j * 4096);
        g.bias[j] = bcomb + j * 64;
        g.C[j] = ATT + (size_t)j * BSZ * 64;
    }
    g.A[2] = g.A[1]; g.W[2] = g.W[1]; g.bias[2] = g.bias[1]; g.C[2] = g.C[1];
    hipLaunchKernelGGL((gemmb10<0, 64, 0, 1>), dim3(1, 256, 2), dim3(256), 0, stream,
                       g, BSZ, 64, 64, 0);

    // ---- losses ----
    hipLaunchKernelGGL(loss_b, dim3(256, 1, 3), dim3(256), 0, stream,
                       ZEP, ZQ, ATT, vq_loss, commit, 1.0f / (float)(BSZ * 64));

    // ---- decoders (interleaved u32 intermediates — r15 best config) ----
    for (int l = 0; l < 3; ++l) {
        g.A[l] = ZQ + (size_t)l * BSZ * 64; g.W[l] = wfp[l][3];
        g.bias[l] = (const float*)d_in[3 + 13 * l + 7];
        g.C[l] = H1 + (size_t)l * BSZ * 256;
    }
    hipLaunchKernelGGL((gemmb10<0, 128, 0, 1>), dim3(2, 256, 3), dim3(256), 0, stream,
                       g, BSZ, 256, 64, 1);
    for (int l = 0; l < 3; ++l) {
        g.A[l] = H1 + (size_t)l * BSZ * 256; g.W[l] = wfp[l][4];
        g.bias[l] = (const float*)d_in[3 + 13 * l + 9];
        g.C[l] = H2 + (size_t)l * BSZ * 256;
    }
    hipLaunchKernelGGL((gemmb10<0, 128, 0, 1>), dim3(2, 256, 3), dim3(256), 0, stream,
                       g, BSZ, 256, 256, 1);
    for (int l = 0; l < 3; ++l) {
        g.A[l] = H2 + (size_t)l * BSZ * 256; g.W[l] = wfp[l][5];
        g.bias[l] = (const float*)d_in[3 + 13 * l + 11];
        g.C[l] = out + (size_t)l * BSZ * 512;
    }
    hipLaunchKernelGGL((gemmb10<0, 128, 0, 0>), dim3(4, 256, 3), dim3(256), 0, stream,
                       g, BSZ, 512, 256, 0);
}